// Round 2
// baseline (1432.300 us; speedup 1.0000x reference)
//
#include <hip/hip_runtime.h>
#include <hip/hip_bf16.h>
#include <cmath>

#define NN 100000
#define NE 1600000
#define FIN 512
#define HD 128
#define NC 40
#define NL 8

typedef __attribute__((ext_vector_type(8))) short bh8;
typedef __attribute__((ext_vector_type(4))) float f4;
typedef __attribute__((ext_vector_type(4))) unsigned int u4;

__device__ __forceinline__ float bflo(unsigned p){ return __uint_as_float(p << 16); }
__device__ __forceinline__ float bfhi(unsigned p){ return __uint_as_float(p & 0xffff0000u); }
__device__ __forceinline__ unsigned short f2bf(float f){
  unsigned u = __float_as_uint(f);
  u += 0x7fffu + ((u >> 16) & 1u);
  return (unsigned short)(u >> 16);
}
__device__ __forceinline__ unsigned pack2(float a, float b){
  return (unsigned)f2bf(a) | ((unsigned)f2bf(b) << 16);
}

// ---------------- CSR build ----------------
__global__ void k_deg(const int* __restrict__ dst, int* __restrict__ deg, int e){
  for (int i = blockIdx.x * blockDim.x + threadIdx.x; i < e; i += gridDim.x * blockDim.x)
    atomicAdd(&deg[dst[i]], 1);
}

__global__ void k_scan(const int* __restrict__ deg, int* __restrict__ offs,
                       int* __restrict__ cur, int n){
  __shared__ int wsum[16];
  __shared__ int carry;
  int t = threadIdx.x, lane = t & 63, wid = t >> 6;
  if (t == 0) carry = 0;
  __syncthreads();
  for (int base = 0; base < n; base += 1024){
    int idx = base + t;
    int v = (idx < n) ? deg[idx] : 0;
    int orig = v;
    #pragma unroll
    for (int off = 1; off < 64; off <<= 1){
      int u = __shfl_up(v, off);
      if (lane >= off) v += u;
    }
    if (lane == 63) wsum[wid] = v;
    __syncthreads();
    if (wid == 0){
      int s = (lane < 16) ? wsum[lane] : 0;
      #pragma unroll
      for (int off = 1; off < 16; off <<= 1){
        int u = __shfl_up(s, off);
        if (lane >= off) s += u;
      }
      if (lane < 16) wsum[lane] = s;
    }
    __syncthreads();
    int wexcl = (wid == 0) ? 0 : wsum[wid - 1];
    int excl = carry + wexcl + (v - orig);
    if (idx < n){ offs[idx] = excl; cur[idx] = excl; }
    int ctot = wsum[15];
    __syncthreads();
    if (t == 0) carry += ctot;
    __syncthreads();
  }
  if (t == 0) offs[n] = carry;
}

__global__ void k_scatter(const int* __restrict__ src, const int* __restrict__ dst,
                          const float* __restrict__ w, int* __restrict__ cur,
                          int* __restrict__ csrc, float* __restrict__ cw, int e){
  for (int i = blockIdx.x * blockDim.x + threadIdx.x; i < e; i += gridDim.x * blockDim.x){
    int d = dst[i];
    int p = atomicAdd(&cur[d], 1);
    csrc[p] = src[i];
    cw[p] = w[i];
  }
}

// ---------------- weight transpose+cast: out[c][k] = bf16(in[k][c]) ----------------
__global__ void k_twt(const float* __restrict__ in, unsigned short* __restrict__ out,
                      int K, int C, int Cpad){
  int total = Cpad * K;
  for (int i = blockIdx.x * blockDim.x + threadIdx.x; i < total; i += gridDim.x * blockDim.x){
    int c = i / K, k = i % K;
    float v = (c < C) ? in[(size_t)k * C + c] : 0.f;
    out[i] = f2bf(v);
  }
}

// ---------------- GEMM0: h0 = relu(x @ W0 + b0), write bf16 to two buffers ----------------
__global__ __launch_bounds__(256) void k_gemm0(const float* __restrict__ X,
                                               const unsigned short* __restrict__ Wt,
                                               const float* __restrict__ b0,
                                               unsigned* __restrict__ Ha,
                                               unsigned* __restrict__ Hb, int n){
  __shared__ __attribute__((aligned(16))) char lds[33792];
  char* ldsA = lds;           // 64 rows x 64 k bf16 = 8192 B (row stride 128 B)
  char* ldsW = lds + 8192;    // 128 c x 64 k bf16 = 16384 B
  float* ldsO = (float*)lds;  // 64 x 132 f32 (reused after compute)
  int t = threadIdx.x;
  int w = t >> 6, lane = t & 63;
  int rowBase = blockIdx.x * 64;
  f4 acc[8];
  #pragma unroll
  for (int i = 0; i < 8; i++) acc[i] = (f4)0.f;

  for (int kk = 0; kk < 8; kk++){
    #pragma unroll
    for (int iter = 0; iter < 2; iter++){
      int r = t / 8 + iter * 32;
      int kc = (t % 8) * 8;
      int grow = rowBase + r;
      float4 f0 = {0,0,0,0}, f1 = {0,0,0,0};
      if (grow < n){
        const float4* p = (const float4*)(X + (size_t)grow * FIN + kk * 64 + kc);
        f0 = p[0]; f1 = p[1];
      }
      u4 pv = { pack2(f0.x, f0.y), pack2(f0.z, f0.w), pack2(f1.x, f1.y), pack2(f1.z, f1.w) };
      *(u4*)(ldsA + r * 128 + ((kc * 2) ^ ((r & 7) << 4))) = pv;
    }
    #pragma unroll
    for (int iter = 0; iter < 4; iter++){
      int c = t / 8 + iter * 32;
      int kc = (t % 8) * 8;
      bh8 v = *(const bh8*)(Wt + (size_t)c * FIN + kk * 64 + kc);
      *(bh8*)(ldsW + c * 128 + ((kc * 2) ^ ((c & 7) << 4))) = v;
    }
    __syncthreads();
    int rowf = (w << 4) + (lane & 15);
    #pragma unroll
    for (int ks = 0; ks < 2; ks++){
      bh8 fa = *(const bh8*)(ldsA + rowf * 128 + ((ks * 64 + (lane >> 4) * 16) ^ ((rowf & 7) << 4)));
      #pragma unroll
      for (int ct = 0; ct < 8; ct++){
        int colf = (ct << 4) + (lane & 15);
        bh8 fb = *(const bh8*)(ldsW + colf * 128 + ((ks * 64 + (lane >> 4) * 16) ^ ((colf & 7) << 4)));
        acc[ct] = __builtin_amdgcn_mfma_f32_16x16x32_bf16(fa, fb, acc[ct], 0, 0, 0);
      }
    }
    __syncthreads();
  }
  // epilogue: relu(acc + b0) -> ldsO (f32, stride 132) -> coalesced bf16 stores
  #pragma unroll
  for (int ct = 0; ct < 8; ct++){
    int colf = (ct << 4) + (lane & 15);
    float bb = b0[colf];
    #pragma unroll
    for (int i = 0; i < 4; i++){
      int r = (w << 4) + ((lane >> 4) << 2) + i;
      float v = acc[ct][i] + bb;
      ldsO[r * 132 + colf] = v > 0.f ? v : 0.f;
    }
  }
  __syncthreads();
  #pragma unroll
  for (int iter = 0; iter < 4; iter++){
    int r = iter * 16 + t / 16;
    int c8 = (t % 16) * 8;
    int grow = rowBase + r;
    if (grow < n){
      float* p = &ldsO[r * 132 + c8];
      u4 pv = { pack2(p[0], p[1]), pack2(p[2], p[3]), pack2(p[4], p[5]), pack2(p[6], p[7]) };
      *(u4*)(Ha + (size_t)grow * 64 + (t % 16) * 4) = pv;
      *(u4*)(Hb + (size_t)grow * 64 + (t % 16) * 4) = pv;
    }
  }
}

// ---------------- aggregation: T[d] = bf16(0.9 * sum_e w_e * H[src_e] + 0.1 * X0[d]) ----------------
__global__ __launch_bounds__(256) void k_agg(const unsigned* __restrict__ H,
                                             const unsigned* __restrict__ X0,
                                             const int* __restrict__ offs,
                                             const int* __restrict__ csrc,
                                             const float* __restrict__ cw,
                                             unsigned* __restrict__ T, int n){
  int gw = (blockIdx.x * blockDim.x + threadIdx.x) >> 6;
  int lane = threadIdx.x & 63;
  int nw = (gridDim.x * blockDim.x) >> 6;
  for (int d = gw; d < n; d += nw){
    int e0 = offs[d], e1 = offs[d + 1];
    float ax = 0.f, ay = 0.f;
    int e = e0;
    for (; e + 2 <= e1; e += 2){
      int s0 = csrc[e], s1 = csrc[e + 1];
      float w0 = cw[e], w1 = cw[e + 1];
      unsigned p0 = H[(size_t)s0 * 64 + lane];
      unsigned p1 = H[(size_t)s1 * 64 + lane];
      ax += w0 * bflo(p0) + w1 * bflo(p1);
      ay += w0 * bfhi(p0) + w1 * bfhi(p1);
    }
    if (e < e1){
      int s = csrc[e]; float wq = cw[e];
      unsigned p = H[(size_t)s * 64 + lane];
      ax += wq * bflo(p); ay += wq * bfhi(p);
    }
    unsigned xp = X0[(size_t)d * 64 + lane];
    float vx = 0.9f * ax + 0.1f * bflo(xp);
    float vy = 0.9f * ay + 0.1f * bfhi(xp);
    T[(size_t)d * 64 + lane] = pack2(vx, vy);
  }
}

// ---------------- layer GEMM: H = relu((1-beta)*T + beta*(T @ W)) ----------------
__global__ __launch_bounds__(256) void k_gemmL(const unsigned short* __restrict__ A,
                                               const unsigned short* __restrict__ Wt,
                                               float beta,
                                               unsigned* __restrict__ Hout, int n){
  __shared__ __attribute__((aligned(16))) char lds[49152];
  char* ldsA = lds;            // 64 x 128 bf16 = 16384 (row stride 256 B)
  char* ldsW = lds + 16384;    // 128 x 128 bf16 = 32768
  float* ldsO = (float*)lds;   // 64 x 132 f32 (reuse)
  int t = threadIdx.x;
  int w = t >> 6, lane = t & 63;
  int rowBase = blockIdx.x * 64;

  #pragma unroll
  for (int iter = 0; iter < 4; iter++){
    int r = t / 16 + iter * 16;
    int kc = (t % 16) * 8;
    int grow = rowBase + r;
    bh8 v = (bh8)(short)0;
    if (grow < n) v = *(const bh8*)(A + (size_t)grow * HD + kc);
    *(bh8*)(ldsA + r * 256 + ((kc * 2) ^ ((r & 7) << 4))) = v;
  }
  #pragma unroll
  for (int iter = 0; iter < 8; iter++){
    int c = t / 16 + iter * 16;
    int kc = (t % 16) * 8;
    bh8 v = *(const bh8*)(Wt + (size_t)c * HD + kc);
    *(bh8*)(ldsW + c * 256 + ((kc * 2) ^ ((c & 7) << 4))) = v;
  }
  __syncthreads();

  f4 acc[8];
  #pragma unroll
  for (int i = 0; i < 8; i++) acc[i] = (f4)0.f;
  int rowf = (w << 4) + (lane & 15);
  #pragma unroll
  for (int ks = 0; ks < 4; ks++){
    bh8 fa = *(const bh8*)(ldsA + rowf * 256 + ((ks * 64 + (lane >> 4) * 16) ^ ((rowf & 7) << 4)));
    #pragma unroll
    for (int ct = 0; ct < 8; ct++){
      int colf = (ct << 4) + (lane & 15);
      bh8 fb = *(const bh8*)(ldsW + colf * 256 + ((ks * 64 + (lane >> 4) * 16) ^ ((colf & 7) << 4)));
      acc[ct] = __builtin_amdgcn_mfma_f32_16x16x32_bf16(fa, fb, acc[ct], 0, 0, 0);
    }
  }

  // epilogue: mix with identity path (tmp re-read from LDS), relu
  float vout[8][4];
  #pragma unroll
  for (int ct = 0; ct < 8; ct++){
    int colf = (ct << 4) + (lane & 15);
    #pragma unroll
    for (int i = 0; i < 4; i++){
      int r = (w << 4) + ((lane >> 4) << 2) + i;
      unsigned short tv = *(const unsigned short*)(ldsA + r * 256 + ((colf * 2) ^ ((r & 7) << 4)));
      float tf = __uint_as_float(((unsigned)tv) << 16);
      float v = (1.f - beta) * tf + beta * acc[ct][i];
      vout[ct][i] = v > 0.f ? v : 0.f;
    }
  }
  __syncthreads();
  #pragma unroll
  for (int ct = 0; ct < 8; ct++){
    int colf = (ct << 4) + (lane & 15);
    #pragma unroll
    for (int i = 0; i < 4; i++){
      int r = (w << 4) + ((lane >> 4) << 2) + i;
      ldsO[r * 132 + colf] = vout[ct][i];
    }
  }
  __syncthreads();
  #pragma unroll
  for (int iter = 0; iter < 4; iter++){
    int r = iter * 16 + t / 16;
    int c8 = (t % 16) * 8;
    int grow = rowBase + r;
    if (grow < n){
      float* p = &ldsO[r * 132 + c8];
      u4 pv = { pack2(p[0], p[1]), pack2(p[2], p[3]), pack2(p[4], p[5]), pack2(p[6], p[7]) };
      *(u4*)(Hout + (size_t)grow * 64 + (t % 16) * 4) = pv;
    }
  }
}

// ---------------- head + log_softmax: wave per row ----------------
__global__ __launch_bounds__(256) void k_final(const unsigned* __restrict__ H,
                                               const unsigned short* __restrict__ W1t,
                                               const float* __restrict__ b1,
                                               float* __restrict__ out, int n){
  int gw = (blockIdx.x * blockDim.x + threadIdx.x) >> 6;
  int lane = threadIdx.x & 63;
  int nw = (gridDim.x * blockDim.x) >> 6;
  for (int row = gw; row < n; row += nw){
    float dot = -3.4e38f;
    if (lane < NC){
      float s = b1[lane];
      const unsigned* hp = H + (size_t)row * 64;
      const unsigned* wp = (const unsigned*)(W1t + (size_t)lane * HD);
      #pragma unroll 8
      for (int k = 0; k < 64; k++){
        unsigned hv = hp[k], wv = wp[k];
        s += bflo(hv) * bflo(wv) + bfhi(hv) * bfhi(wv);
      }
      dot = s;
    }
    float m = dot;
    #pragma unroll
    for (int off = 32; off; off >>= 1) m = fmaxf(m, __shfl_xor(m, off));
    float ex = (lane < NC) ? __expf(dot - m) : 0.f;
    float ssum = ex;
    #pragma unroll
    for (int off = 32; off; off >>= 1) ssum += __shfl_xor(ssum, off);
    float ls = __logf(ssum);
    if (lane < NC) out[(size_t)row * NC + lane] = dot - m - ls;
  }
}

extern "C" void kernel_launch(void* const* d_in, const int* in_sizes, int n_in,
                              void* d_out, int out_size, void* d_ws, size_t ws_size,
                              hipStream_t stream){
  const float* x  = (const float*)d_in[0];
  const int*   ei = (const int*)d_in[1];
  const float* ew = (const float*)d_in[2];
  const float* W0 = (const float*)d_in[3];
  const float* b0 = (const float*)d_in[4];
  const float* cW = (const float*)d_in[5];
  const float* W1 = (const float*)d_in[6];
  const float* b1 = (const float*)d_in[7];
  float* out = (float*)d_out;
  const int* src = ei;
  const int* dst = ei + NE;

  char* ws = (char*)d_ws;
  size_t off = 0;
  auto alloc = [&](size_t bytes) -> char* {
    char* p = ws + off;
    off += (bytes + 255) & ~(size_t)255;
    return p;
  };
  unsigned* x0b = (unsigned*)alloc((size_t)NN * 64 * 4);        // x0 bf16x2
  unsigned* hb  = (unsigned*)alloc((size_t)NN * 64 * 4);        // h bf16x2
  unsigned* tb  = (unsigned*)alloc((size_t)NN * 64 * 4);        // tmp bf16x2
  unsigned short* W0t = (unsigned short*)alloc((size_t)FIN * HD * 2);
  unsigned short* cWt = (unsigned short*)alloc((size_t)NL * HD * HD * 2);
  unsigned short* W1t = (unsigned short*)alloc((size_t)48 * HD * 2);
  int*   deg  = (int*)alloc((size_t)NN * 4);
  int*   offs = (int*)alloc((size_t)(NN + 1) * 4);
  int*   cur  = (int*)alloc((size_t)NN * 4);
  int*   csrc = (int*)alloc((size_t)NE * 4);
  float* cwv  = (float*)alloc((size_t)NE * 4);

  (void)hipMemsetAsync(deg, 0, (size_t)NN * 4, stream);
  hipLaunchKernelGGL(k_deg, dim3(1024), dim3(256), 0, stream, dst, deg, NE);
  hipLaunchKernelGGL(k_scan, dim3(1), dim3(1024), 0, stream, deg, offs, cur, NN);
  hipLaunchKernelGGL(k_scatter, dim3(1024), dim3(256), 0, stream, src, dst, ew, cur, csrc, cwv, NE);
  hipLaunchKernelGGL(k_twt, dim3(256), dim3(256), 0, stream, W0, W0t, FIN, HD, HD);
  for (int l = 0; l < NL; l++)
    hipLaunchKernelGGL(k_twt, dim3(64), dim3(256), 0, stream,
                       cW + (size_t)l * HD * HD, cWt + (size_t)l * HD * HD, HD, HD, HD);
  hipLaunchKernelGGL(k_twt, dim3(24), dim3(256), 0, stream, W1, W1t, HD, NC, 48);

  int gblocks = (NN + 63) / 64;
  hipLaunchKernelGGL(k_gemm0, dim3(gblocks), dim3(256), 0, stream, x, W0t, b0, x0b, hb, NN);
  for (int l = 0; l < NL; l++){
    float beta = logf(0.5f / (float)(l + 1) + 1.0f);
    hipLaunchKernelGGL(k_agg, dim3(2048), dim3(256), 0, stream, hb, x0b, offs, csrc, cwv, tb, NN);
    hipLaunchKernelGGL(k_gemmL, dim3(gblocks), dim3(256), 0, stream,
                       (const unsigned short*)tb, cWt + (size_t)l * HD * HD, beta, hb, NN);
  }
  hipLaunchKernelGGL(k_final, dim3(2048), dim3(256), 0, stream, hb, W1t, b1, out, NN);
}

// Round 3
// 1049.174 us; speedup vs baseline: 1.3652x; 1.3652x over previous
//
#include <hip/hip_runtime.h>
#include <hip/hip_bf16.h>
#include <cmath>

#define NN 100000
#define NE 1600000
#define FIN 512
#define HD 128
#define NC 40
#define NL 8

typedef __attribute__((ext_vector_type(8))) short bh8;
typedef __attribute__((ext_vector_type(4))) float f4;
typedef __attribute__((ext_vector_type(4))) unsigned int u4;

__device__ __forceinline__ float bflo(unsigned p){ return __uint_as_float(p << 16); }
__device__ __forceinline__ float bfhi(unsigned p){ return __uint_as_float(p & 0xffff0000u); }
__device__ __forceinline__ unsigned short f2bf(float f){
  unsigned u = __float_as_uint(f);
  u += 0x7fffu + ((u >> 16) & 1u);
  return (unsigned short)(u >> 16);
}
__device__ __forceinline__ unsigned pack2(float a, float b){
  return (unsigned)f2bf(a) | ((unsigned)f2bf(b) << 16);
}

// ---------------- CSR build ----------------
__global__ void k_deg(const int* __restrict__ dst, int* __restrict__ deg, int e){
  for (int i = blockIdx.x * blockDim.x + threadIdx.x; i < e; i += gridDim.x * blockDim.x)
    atomicAdd(&deg[dst[i]], 1);
}

__global__ void k_scan(const int* __restrict__ deg, int* __restrict__ offs,
                       int* __restrict__ cur, int n){
  __shared__ int wsum[16];
  __shared__ int carry;
  int t = threadIdx.x, lane = t & 63, wid = t >> 6;
  if (t == 0) carry = 0;
  __syncthreads();
  for (int base = 0; base < n; base += 1024){
    int idx = base + t;
    int v = (idx < n) ? deg[idx] : 0;
    int orig = v;
    #pragma unroll
    for (int off = 1; off < 64; off <<= 1){
      int u = __shfl_up(v, off);
      if (lane >= off) v += u;
    }
    if (lane == 63) wsum[wid] = v;
    __syncthreads();
    if (wid == 0){
      int s = (lane < 16) ? wsum[lane] : 0;
      #pragma unroll
      for (int off = 1; off < 16; off <<= 1){
        int u = __shfl_up(s, off);
        if (lane >= off) s += u;
      }
      if (lane < 16) wsum[lane] = s;
    }
    __syncthreads();
    int wexcl = (wid == 0) ? 0 : wsum[wid - 1];
    int excl = carry + wexcl + (v - orig);
    if (idx < n){ offs[idx] = excl; cur[idx] = excl; }
    int ctot = wsum[15];
    __syncthreads();
    if (t == 0) carry += ctot;
    __syncthreads();
  }
  if (t == 0) offs[n] = carry;
}

__global__ void k_scatter(const int* __restrict__ src, const int* __restrict__ dst,
                          const float* __restrict__ w, int* __restrict__ cur,
                          int* __restrict__ csrc, float* __restrict__ cw, int e){
  for (int i = blockIdx.x * blockDim.x + threadIdx.x; i < e; i += gridDim.x * blockDim.x){
    int d = dst[i];
    int p = atomicAdd(&cur[d], 1);
    csrc[p] = src[i];
    cw[p] = w[i];
  }
}

// ---------------- weight transpose+cast: out[c][k] = bf16(in[k][c]) ----------------
__global__ void k_twt(const float* __restrict__ in, unsigned short* __restrict__ out,
                      int K, int C, int Cpad){
  int total = Cpad * K;
  for (int i = blockIdx.x * blockDim.x + threadIdx.x; i < total; i += gridDim.x * blockDim.x){
    int c = i / K, k = i % K;
    float v = (c < C) ? in[(size_t)k * C + c] : 0.f;
    out[i] = f2bf(v);
  }
}

// ---------------- GEMM0: h0 = relu(x @ W0 + b0), write bf16 to two buffers ----------------
__global__ __launch_bounds__(256) void k_gemm0(const float* __restrict__ X,
                                               const unsigned short* __restrict__ Wt,
                                               const float* __restrict__ b0,
                                               unsigned* __restrict__ Ha,
                                               unsigned* __restrict__ Hb, int n){
  __shared__ __attribute__((aligned(16))) char lds[33792];
  char* ldsA = lds;           // 64 rows x 64 k bf16 = 8192 B (row stride 128 B)
  char* ldsW = lds + 8192;    // 128 c x 64 k bf16 = 16384 B
  float* ldsO = (float*)lds;  // 64 x 132 f32 (reused after compute)
  int t = threadIdx.x;
  int w = t >> 6, lane = t & 63;
  int rowBase = blockIdx.x * 64;
  f4 acc[8];
  #pragma unroll
  for (int i = 0; i < 8; i++) acc[i] = (f4)0.f;

  for (int kk = 0; kk < 8; kk++){
    #pragma unroll
    for (int iter = 0; iter < 2; iter++){
      int r = t / 8 + iter * 32;
      int kc = (t % 8) * 8;
      int grow = rowBase + r;
      float4 f0 = {0,0,0,0}, f1 = {0,0,0,0};
      if (grow < n){
        const float4* p = (const float4*)(X + (size_t)grow * FIN + kk * 64 + kc);
        f0 = p[0]; f1 = p[1];
      }
      u4 pv = { pack2(f0.x, f0.y), pack2(f0.z, f0.w), pack2(f1.x, f1.y), pack2(f1.z, f1.w) };
      *(u4*)(ldsA + r * 128 + ((kc * 2) ^ ((r & 7) << 4))) = pv;
    }
    #pragma unroll
    for (int iter = 0; iter < 4; iter++){
      int c = t / 8 + iter * 32;
      int kc = (t % 8) * 8;
      bh8 v = *(const bh8*)(Wt + (size_t)c * FIN + kk * 64 + kc);
      *(bh8*)(ldsW + c * 128 + ((kc * 2) ^ ((c & 7) << 4))) = v;
    }
    __syncthreads();
    int rowf = (w << 4) + (lane & 15);
    #pragma unroll
    for (int ks = 0; ks < 2; ks++){
      bh8 fa = *(const bh8*)(ldsA + rowf * 128 + ((ks * 64 + (lane >> 4) * 16) ^ ((rowf & 7) << 4)));
      #pragma unroll
      for (int ct = 0; ct < 8; ct++){
        int colf = (ct << 4) + (lane & 15);
        bh8 fb = *(const bh8*)(ldsW + colf * 128 + ((ks * 64 + (lane >> 4) * 16) ^ ((colf & 7) << 4)));
        acc[ct] = __builtin_amdgcn_mfma_f32_16x16x32_bf16(fa, fb, acc[ct], 0, 0, 0);
      }
    }
    __syncthreads();
  }
  // epilogue: relu(acc + b0) -> ldsO (f32, stride 132) -> coalesced bf16 stores
  #pragma unroll
  for (int ct = 0; ct < 8; ct++){
    int colf = (ct << 4) + (lane & 15);
    float bb = b0[colf];
    #pragma unroll
    for (int i = 0; i < 4; i++){
      int r = (w << 4) + ((lane >> 4) << 2) + i;
      float v = acc[ct][i] + bb;
      ldsO[r * 132 + colf] = v > 0.f ? v : 0.f;
    }
  }
  __syncthreads();
  #pragma unroll
  for (int iter = 0; iter < 4; iter++){
    int r = iter * 16 + t / 16;
    int c8 = (t % 16) * 8;
    int grow = rowBase + r;
    if (grow < n){
      float* p = &ldsO[r * 132 + c8];
      u4 pv = { pack2(p[0], p[1]), pack2(p[2], p[3]), pack2(p[4], p[5]), pack2(p[6], p[7]) };
      *(u4*)(Ha + (size_t)grow * 64 + (t % 16) * 4) = pv;
      *(u4*)(Hb + (size_t)grow * 64 + (t % 16) * 4) = pv;
    }
  }
}

// ---------------- aggregation: T[d] = bf16(0.9 * sum_e w_e * H[src_e] + 0.1 * X0[d]) ----------------
// wave = 4 quads of 16 lanes; each quad gathers one full 256B row per iter (dwordx4/lane)
__global__ __launch_bounds__(256) void k_agg(const unsigned* __restrict__ H,
                                             const unsigned* __restrict__ X0,
                                             const int* __restrict__ offs,
                                             const int* __restrict__ csrc,
                                             const float* __restrict__ cw,
                                             unsigned* __restrict__ T, int n){
  int gw = (blockIdx.x * blockDim.x + threadIdx.x) >> 6;
  int lane = threadIdx.x & 63;
  int q = lane >> 4, l16 = lane & 15;
  int nw = (gridDim.x * blockDim.x) >> 6;
  for (int d = gw; d < n; d += nw){
    int e0 = offs[d], e1 = offs[d + 1];
    float a0=0.f,a1=0.f,a2=0.f,a3=0.f,a4=0.f,a5=0.f,a6=0.f,a7=0.f;
    for (int e = e0 + q; e < e1; e += 4){
      int s = csrc[e]; float wq = cw[e];
      u4 p = *(const u4*)(H + (size_t)s * 64 + l16 * 4);
      a0 += wq * bflo(p.x); a1 += wq * bfhi(p.x);
      a2 += wq * bflo(p.y); a3 += wq * bfhi(p.y);
      a4 += wq * bflo(p.z); a5 += wq * bfhi(p.z);
      a6 += wq * bflo(p.w); a7 += wq * bfhi(p.w);
    }
    // combine across the 4 quads
    a0 += __shfl_xor(a0,16); a0 += __shfl_xor(a0,32);
    a1 += __shfl_xor(a1,16); a1 += __shfl_xor(a1,32);
    a2 += __shfl_xor(a2,16); a2 += __shfl_xor(a2,32);
    a3 += __shfl_xor(a3,16); a3 += __shfl_xor(a3,32);
    a4 += __shfl_xor(a4,16); a4 += __shfl_xor(a4,32);
    a5 += __shfl_xor(a5,16); a5 += __shfl_xor(a5,32);
    a6 += __shfl_xor(a6,16); a6 += __shfl_xor(a6,32);
    a7 += __shfl_xor(a7,16); a7 += __shfl_xor(a7,32);
    if (q == 0){
      u4 xp = *(const u4*)(X0 + (size_t)d * 64 + l16 * 4);
      float v0 = 0.9f*a0 + 0.1f*bflo(xp.x), v1 = 0.9f*a1 + 0.1f*bfhi(xp.x);
      float v2 = 0.9f*a2 + 0.1f*bflo(xp.y), v3 = 0.9f*a3 + 0.1f*bfhi(xp.y);
      float v4 = 0.9f*a4 + 0.1f*bflo(xp.z), v5 = 0.9f*a5 + 0.1f*bfhi(xp.z);
      float v6 = 0.9f*a6 + 0.1f*bflo(xp.w), v7 = 0.9f*a7 + 0.1f*bfhi(xp.w);
      u4 ov = { pack2(v0,v1), pack2(v2,v3), pack2(v4,v5), pack2(v6,v7) };
      *(u4*)(T + (size_t)d * 64 + l16 * 4) = ov;
    }
  }
}

// ---------------- layer GEMM: H = relu((1-beta)*T + beta*(T @ W)) ----------------
__global__ __launch_bounds__(256) void k_gemmL(const unsigned short* __restrict__ A,
                                               const unsigned short* __restrict__ Wt,
                                               float beta,
                                               unsigned* __restrict__ Hout, int n){
  __shared__ __attribute__((aligned(16))) char lds[49152];
  char* ldsA = lds;            // 64 x 128 bf16 = 16384 (row stride 256 B)
  char* ldsW = lds + 16384;    // 128 x 128 bf16 = 32768
  float* ldsO = (float*)lds;   // 64 x 132 f32 (reuse)
  int t = threadIdx.x;
  int w = t >> 6, lane = t & 63;
  int rowBase = blockIdx.x * 64;

  #pragma unroll
  for (int iter = 0; iter < 4; iter++){
    int r = t / 16 + iter * 16;
    int kc = (t % 16) * 8;
    int grow = rowBase + r;
    bh8 v = (bh8)(short)0;
    if (grow < n) v = *(const bh8*)(A + (size_t)grow * HD + kc);
    *(bh8*)(ldsA + r * 256 + ((kc * 2) ^ ((r & 7) << 4))) = v;
  }
  #pragma unroll
  for (int iter = 0; iter < 8; iter++){
    int c = t / 16 + iter * 16;
    int kc = (t % 16) * 8;
    bh8 v = *(const bh8*)(Wt + (size_t)c * HD + kc);
    *(bh8*)(ldsW + c * 256 + ((kc * 2) ^ ((c & 7) << 4))) = v;
  }
  __syncthreads();

  f4 acc[8];
  #pragma unroll
  for (int i = 0; i < 8; i++) acc[i] = (f4)0.f;
  int rowf = (w << 4) + (lane & 15);
  #pragma unroll
  for (int ks = 0; ks < 4; ks++){
    bh8 fa = *(const bh8*)(ldsA + rowf * 256 + ((ks * 64 + (lane >> 4) * 16) ^ ((rowf & 7) << 4)));
    #pragma unroll
    for (int ct = 0; ct < 8; ct++){
      int colf = (ct << 4) + (lane & 15);
      bh8 fb = *(const bh8*)(ldsW + colf * 256 + ((ks * 64 + (lane >> 4) * 16) ^ ((colf & 7) << 4)));
      acc[ct] = __builtin_amdgcn_mfma_f32_16x16x32_bf16(fa, fb, acc[ct], 0, 0, 0);
    }
  }

  // epilogue: mix with identity path (tmp re-read from LDS), relu
  float vout[8][4];
  #pragma unroll
  for (int ct = 0; ct < 8; ct++){
    int colf = (ct << 4) + (lane & 15);
    #pragma unroll
    for (int i = 0; i < 4; i++){
      int r = (w << 4) + ((lane >> 4) << 2) + i;
      unsigned short tv = *(const unsigned short*)(ldsA + r * 256 + ((colf * 2) ^ ((r & 7) << 4)));
      float tf = __uint_as_float(((unsigned)tv) << 16);
      float v = (1.f - beta) * tf + beta * acc[ct][i];
      vout[ct][i] = v > 0.f ? v : 0.f;
    }
  }
  __syncthreads();
  #pragma unroll
  for (int ct = 0; ct < 8; ct++){
    int colf = (ct << 4) + (lane & 15);
    #pragma unroll
    for (int i = 0; i < 4; i++){
      int r = (w << 4) + ((lane >> 4) << 2) + i;
      ldsO[r * 132 + colf] = vout[ct][i];
    }
  }
  __syncthreads();
  #pragma unroll
  for (int iter = 0; iter < 4; iter++){
    int r = iter * 16 + t / 16;
    int c8 = (t % 16) * 8;
    int grow = rowBase + r;
    if (grow < n){
      float* p = &ldsO[r * 132 + c8];
      u4 pv = { pack2(p[0], p[1]), pack2(p[2], p[3]), pack2(p[4], p[5]), pack2(p[6], p[7]) };
      *(u4*)(Hout + (size_t)grow * 64 + (t % 16) * 4) = pv;
    }
  }
}

// ---------------- head + log_softmax: MFMA 64x48 tile, in-register softmax ----------------
__global__ __launch_bounds__(256) void k_final(const unsigned* __restrict__ H,
                                               const unsigned short* __restrict__ W1t, // [48][128]
                                               const float* __restrict__ b1,
                                               float* __restrict__ out, int n){
  __shared__ __attribute__((aligned(16))) char lds[16384 + 12288];
  char* ldsA = lds;            // 64 x 128 bf16, row stride 256 B, swizzled
  char* ldsW = lds + 16384;    // 48 x 128 bf16
  int t = threadIdx.x;
  int w = t >> 6, lane = t & 63;
  int l15 = lane & 15;
  int rowBase = blockIdx.x * 64;
  const unsigned short* Hs = (const unsigned short*)H;

  #pragma unroll
  for (int iter = 0; iter < 4; iter++){
    int r = t / 16 + iter * 16;
    int kc = (t % 16) * 8;
    int grow = rowBase + r;
    bh8 v = (bh8)(short)0;
    if (grow < n) v = *(const bh8*)(Hs + (size_t)grow * HD + kc);
    *(bh8*)(ldsA + r * 256 + ((kc * 2) ^ ((r & 7) << 4))) = v;
  }
  #pragma unroll
  for (int iter = 0; iter < 3; iter++){
    int c = t / 16 + iter * 16;
    int kc = (t % 16) * 8;
    bh8 v = *(const bh8*)(W1t + (size_t)c * HD + kc);
    *(bh8*)(ldsW + c * 256 + ((kc * 2) ^ ((c & 7) << 4))) = v;
  }
  __syncthreads();

  f4 acc[3];
  #pragma unroll
  for (int i = 0; i < 3; i++) acc[i] = (f4)0.f;
  int rowf = (w << 4) + l15;
  #pragma unroll
  for (int ks = 0; ks < 4; ks++){
    bh8 fa = *(const bh8*)(ldsA + rowf * 256 + ((ks * 64 + (lane >> 4) * 16) ^ ((rowf & 7) << 4)));
    #pragma unroll
    for (int ct = 0; ct < 3; ct++){
      int colf = (ct << 4) + l15;
      bh8 fb = *(const bh8*)(ldsW + colf * 256 + ((ks * 64 + (lane >> 4) * 16) ^ ((colf & 7) << 4)));
      acc[ct] = __builtin_amdgcn_mfma_f32_16x16x32_bf16(fa, fb, acc[ct], 0, 0, 0);
    }
  }

  float bias0 = b1[l15];
  float bias1 = b1[16 + l15];
  bool v2ok = (l15 < 8);
  float bias2 = v2ok ? b1[32 + l15] : 0.f;

  #pragma unroll
  for (int i = 0; i < 4; i++){
    int r = rowBase + (w << 4) + ((lane >> 4) << 2) + i;
    float v0 = acc[0][i] + bias0;
    float v1 = acc[1][i] + bias1;
    float v2 = v2ok ? (acc[2][i] + bias2) : -1e30f;
    float m = fmaxf(fmaxf(v0, v1), v2);
    #pragma unroll
    for (int off = 1; off < 16; off <<= 1) m = fmaxf(m, __shfl_xor(m, off));
    float e0 = __expf(v0 - m), e1 = __expf(v1 - m);
    float e2 = v2ok ? __expf(v2 - m) : 0.f;
    float s = e0 + e1 + e2;
    #pragma unroll
    for (int off = 1; off < 16; off <<= 1) s += __shfl_xor(s, off);
    float ls = m + __logf(s);
    if (r < n){
      out[(size_t)r * NC + l15] = v0 - ls;
      out[(size_t)r * NC + 16 + l15] = v1 - ls;
      if (v2ok) out[(size_t)r * NC + 32 + l15] = v2 - ls;
    }
  }
}

extern "C" void kernel_launch(void* const* d_in, const int* in_sizes, int n_in,
                              void* d_out, int out_size, void* d_ws, size_t ws_size,
                              hipStream_t stream){
  const float* x  = (const float*)d_in[0];
  const int*   ei = (const int*)d_in[1];
  const float* ew = (const float*)d_in[2];
  const float* W0 = (const float*)d_in[3];
  const float* b0 = (const float*)d_in[4];
  const float* cW = (const float*)d_in[5];
  const float* W1 = (const float*)d_in[6];
  const float* b1 = (const float*)d_in[7];
  float* out = (float*)d_out;
  const int* src = ei;
  const int* dst = ei + NE;

  char* ws = (char*)d_ws;
  size_t off = 0;
  auto alloc = [&](size_t bytes) -> char* {
    char* p = ws + off;
    off += (bytes + 255) & ~(size_t)255;
    return p;
  };
  unsigned* x0b = (unsigned*)alloc((size_t)NN * 64 * 4);        // x0 bf16x2
  unsigned* hb  = (unsigned*)alloc((size_t)NN * 64 * 4);        // h bf16x2
  unsigned* tb  = (unsigned*)alloc((size_t)NN * 64 * 4);        // tmp bf16x2
  unsigned short* W0t = (unsigned short*)alloc((size_t)FIN * HD * 2);
  unsigned short* cWt = (unsigned short*)alloc((size_t)NL * HD * HD * 2);
  unsigned short* W1t = (unsigned short*)alloc((size_t)48 * HD * 2);
  int*   deg  = (int*)alloc((size_t)NN * 4);
  int*   offs = (int*)alloc((size_t)(NN + 1) * 4);
  int*   cur  = (int*)alloc((size_t)NN * 4);
  int*   csrc = (int*)alloc((size_t)NE * 4);
  float* cwv  = (float*)alloc((size_t)NE * 4);

  (void)hipMemsetAsync(deg, 0, (size_t)NN * 4, stream);
  hipLaunchKernelGGL(k_deg, dim3(1024), dim3(256), 0, stream, dst, deg, NE);
  hipLaunchKernelGGL(k_scan, dim3(1), dim3(1024), 0, stream, deg, offs, cur, NN);
  hipLaunchKernelGGL(k_scatter, dim3(1024), dim3(256), 0, stream, src, dst, ew, cur, csrc, cwv, NE);
  hipLaunchKernelGGL(k_twt, dim3(256), dim3(256), 0, stream, W0, W0t, FIN, HD, HD);
  for (int l = 0; l < NL; l++)
    hipLaunchKernelGGL(k_twt, dim3(64), dim3(256), 0, stream,
                       cW + (size_t)l * HD * HD, cWt + (size_t)l * HD * HD, HD, HD, HD);
  hipLaunchKernelGGL(k_twt, dim3(24), dim3(256), 0, stream, W1, W1t, HD, NC, 48);

  int gblocks = (NN + 63) / 64;
  hipLaunchKernelGGL(k_gemm0, dim3(gblocks), dim3(256), 0, stream, x, W0t, b0, x0b, hb, NN);
  for (int l = 0; l < NL; l++){
    float beta = logf(0.5f / (float)(l + 1) + 1.0f);
    hipLaunchKernelGGL(k_agg, dim3(2048), dim3(256), 0, stream, hb, x0b, offs, csrc, cwv, tb, NN);
    hipLaunchKernelGGL(k_gemmL, dim3(gblocks), dim3(256), 0, stream,
                       (const unsigned short*)tb, cWt + (size_t)l * HD * HD, beta, hb, NN);
  }
  hipLaunchKernelGGL(k_final, dim3(gblocks), dim3(256), 0, stream, hb, W1t, b1, out, NN);
}